// Round 1
// baseline (146.755 us; speedup 1.0000x reference)
//
#include <hip/hip_runtime.h>

// One thread = one row of the batch.
// Weights are read with wave-uniform indices through __restrict__ const
// pointers -> compiler emits s_load + v_fmac with SGPR operand (no LDS, no
// per-lane weight traffic). x read as float4, double-buffered one 8-k chunk
// ahead; output written as 6 aligned float4 (row*96 B, 96 % 16 == 0).

__global__ __launch_bounds__(256, 4)
void bd_mlp_kernel(const float* __restrict__ x,
                   const float* __restrict__ Win,    // [64][32]
                   const float* __restrict__ Wh,     // [4][32][32]
                   const float* __restrict__ Wout,   // [32][24]
                   float* __restrict__ out,          // [B][24]
                   int B)
{
    int row = blockIdx.x * blockDim.x + threadIdx.x;
    if (row >= B) return;

    const float4* __restrict__ x4 =
        reinterpret_cast<const float4*>(x) + (size_t)row * 16;

    float h[32];
#pragma unroll
    for (int j = 0; j < 32; ++j) h[j] = 0.f;

    // ---- input layer: h = relu(x @ Win), k-loop in chunks of 8, double-buffered x
    float4 a0 = x4[0];
    float4 b0 = x4[1];
    for (int kc = 0; kc < 8; ++kc) {
        // prefetch next chunk (wraps to 0 on last iter -> harmless L1 hit)
        int nk = (kc + 1) & 7;
        float4 a1 = x4[2 * nk];
        float4 b1 = x4[2 * nk + 1];

        float xk[8] = {a0.x, a0.y, a0.z, a0.w, b0.x, b0.y, b0.z, b0.w};
        const float* __restrict__ wrow = Win + kc * 8 * 32;
#pragma unroll
        for (int kk = 0; kk < 8; ++kk) {
#pragma unroll
            for (int j = 0; j < 32; ++j) {
                h[j] = fmaf(xk[kk], wrow[kk * 32 + j], h[j]);
            }
        }
        a0 = a1; b0 = b1;
    }
#pragma unroll
    for (int j = 0; j < 32; ++j) h[j] = fmaxf(h[j], 0.f);

    // ---- 4 block-diagonal hidden layers (4 blocks of 8x8), relu
    for (int l = 0; l < 4; ++l) {
        const float* __restrict__ wl = Wh + l * 1024;
        float hn[32];
#pragma unroll
        for (int blk = 0; blk < 4; ++blk) {
#pragma unroll
            for (int jj = 0; jj < 8; ++jj) {
                float acc = 0.f;
#pragma unroll
                for (int kk = 0; kk < 8; ++kk) {
                    acc = fmaf(h[blk * 8 + kk],
                               wl[(blk * 8 + kk) * 32 + blk * 8 + jj],
                               acc);
                }
                hn[blk * 8 + jj] = fmaxf(acc, 0.f);
            }
        }
#pragma unroll
        for (int j = 0; j < 32; ++j) h[j] = hn[j];
    }

    // ---- block-diagonal output layer: 8 blocks of 4x3, no activation
    float o[24];
#pragma unroll
    for (int i = 0; i < 8; ++i) {
#pragma unroll
        for (int c = 0; c < 3; ++c) {
            float acc = 0.f;
#pragma unroll
            for (int s = 0; s < 4; ++s) {
                acc = fmaf(h[4 * i + s],
                           Wout[(4 * i + s) * 24 + 3 * i + c],
                           acc);
            }
            o[3 * i + c] = acc;
        }
    }

    float4* __restrict__ o4 = reinterpret_cast<float4*>(out) + (size_t)row * 6;
#pragma unroll
    for (int q = 0; q < 6; ++q) {
        o4[q] = make_float4(o[4 * q + 0], o[4 * q + 1],
                            o[4 * q + 2], o[4 * q + 3]);
    }
}

extern "C" void kernel_launch(void* const* d_in, const int* in_sizes, int n_in,
                              void* d_out, int out_size, void* d_ws, size_t ws_size,
                              hipStream_t stream)
{
    const float* x    = (const float*)d_in[0];  // [B,64]
    const float* Win  = (const float*)d_in[1];  // [64,32]
    const float* Wh   = (const float*)d_in[2];  // [4,32,32]
    const float* Wout = (const float*)d_in[3];  // [32,24]
    float* out        = (float*)d_out;          // [B,24]

    int B = in_sizes[0] / 64;
    int threads = 256;
    int blocks = (B + threads - 1) / threads;
    bd_mlp_kernel<<<blocks, threads, 0, stream>>>(x, Win, Wh, Wout, out, B);
}

// Round 2
// 140.183 us; speedup vs baseline: 1.0469x; 1.0469x over previous
//
#include <hip/hip_runtime.h>

// Wave-local LDS-staged batched MLP.
// Each wave owns 64 rows. x[64 rows][64 cols] is staged through LDS in 4
// chunks of 16 columns:
//   - global load (coalesced): instr i, lane t reads row (t>>2)+16*i,
//     float4 (t&3) of the chunk -> 16 full 64-B cache lines per instr.
//   - LDS tile row stride = 20 words (16 cols + 4 pad). Start bank-quad of a
//     b128 access = (5*row + f4) mod 8, 5 coprime with 8 -> conflict-free
//     ds_write_b128 and ds_read_b128.
//   - chunk c+1 is prefetched into registers while chunk c's 512 FMAs run,
//     so HBM latency hides inside a single wave (no __syncthreads anywhere).
// Input layer accumulates h over column chunks (exact k-split), then 4
// block-diagonal 8x8 hidden layers + 8x(4x3) output layer, all weights read
// with wave-uniform indices -> s_load + SGPR-operand v_fmac.

#define ROWSTRIDE 20  // floats per LDS row: 16 data + 4 pad

__global__ __launch_bounds__(256, 6)
void bd_mlp_kernel(const float* __restrict__ x,
                   const float* __restrict__ Win,    // [64][32]
                   const float* __restrict__ Wh,     // [4][32][32]
                   const float* __restrict__ Wout,   // [32][24]
                   float* __restrict__ out,          // [B][24]
                   int B)
{
    __shared__ __align__(16) float lds[4][64 * ROWSTRIDE];

    const int tid  = threadIdx.x;
    const int wid  = tid >> 6;
    const int lane = tid & 63;

    const int rowbase = blockIdx.x * 256 + wid * 64;  // this wave's 64 rows
    const int row     = rowbase + lane;

    float* __restrict__ wbuf = lds[wid];

    float h[32];
#pragma unroll
    for (int j = 0; j < 32; ++j) h[j] = 0.f;

    const bool full = (rowbase + 64 <= B);  // wave-uniform

    if (full) {
        // staging addresses
        const int r0 = lane >> 2;      // row within 16-row group
        const int f0 = lane & 3;       // float4 within 16-col chunk
        const float* __restrict__ gsrc =
            x + (size_t)rowbase * 64 + (size_t)r0 * 64 + f0 * 4;
        float* __restrict__ wdst = wbuf + r0 * ROWSTRIDE + f0 * 4;
        const float* __restrict__ rsrc = wbuf + lane * ROWSTRIDE;

        float4 p0, p1, p2, p3;
        // prologue: chunk 0 global->reg
        p0 = *reinterpret_cast<const float4*>(gsrc +    0);
        p1 = *reinterpret_cast<const float4*>(gsrc + 1024);
        p2 = *reinterpret_cast<const float4*>(gsrc + 2048);
        p3 = *reinterpret_cast<const float4*>(gsrc + 3072);

#pragma unroll
        for (int c = 0; c < 4; ++c) {
            // reg -> LDS (write-after-read of previous chunk's reads is
            // wave-local; compiler orders DS ops via lgkmcnt)
            *reinterpret_cast<float4*>(wdst + 0 * 16 * ROWSTRIDE) = p0;
            *reinterpret_cast<float4*>(wdst + 1 * 16 * ROWSTRIDE) = p1;
            *reinterpret_cast<float4*>(wdst + 2 * 16 * ROWSTRIDE) = p2;
            *reinterpret_cast<float4*>(wdst + 3 * 16 * ROWSTRIDE) = p3;

            // prefetch next chunk into registers
            if (c < 3) {
                const float* g = gsrc + (c + 1) * 16;
                p0 = *reinterpret_cast<const float4*>(g +    0);
                p1 = *reinterpret_cast<const float4*>(g + 1024);
                p2 = *reinterpret_cast<const float4*>(g + 2048);
                p3 = *reinterpret_cast<const float4*>(g + 3072);
            }

            // consume chunk c: 16 columns, 4 at a time
#pragma unroll
            for (int q = 0; q < 4; ++q) {
                const float4 xv =
                    *reinterpret_cast<const float4*>(rsrc + 4 * q);
                const float* __restrict__ wp = Win + (c * 16 + q * 4) * 32;
#pragma unroll
                for (int j = 0; j < 32; ++j)
                    h[j] = fmaf(xv.x, wp[0 * 32 + j], h[j]);
#pragma unroll
                for (int j = 0; j < 32; ++j)
                    h[j] = fmaf(xv.y, wp[1 * 32 + j], h[j]);
#pragma unroll
                for (int j = 0; j < 32; ++j)
                    h[j] = fmaf(xv.z, wp[2 * 32 + j], h[j]);
#pragma unroll
                for (int j = 0; j < 32; ++j)
                    h[j] = fmaf(xv.w, wp[3 * 32 + j], h[j]);
            }
        }
    } else if (row < B) {
        // tail block (unused when B % 256 == 0): direct per-row loads
        const float* __restrict__ xr = x + (size_t)row * 64;
        for (int k = 0; k < 64; ++k) {
            const float xv = xr[k];
            const float* __restrict__ wp = Win + k * 32;
#pragma unroll
            for (int j = 0; j < 32; ++j) h[j] = fmaf(xv, wp[j], h[j]);
        }
    }

#pragma unroll
    for (int j = 0; j < 32; ++j) h[j] = fmaxf(h[j], 0.f);

    // ---- 4 block-diagonal hidden layers (4 blocks of 8x8), relu
#pragma unroll
    for (int l = 0; l < 4; ++l) {
        const float* __restrict__ wl = Wh + l * 1024;
        float hn[32];
#pragma unroll
        for (int blk = 0; blk < 4; ++blk) {
#pragma unroll
            for (int jj = 0; jj < 8; ++jj) {
                float acc = 0.f;
#pragma unroll
                for (int kk = 0; kk < 8; ++kk) {
                    acc = fmaf(h[blk * 8 + kk],
                               wl[(blk * 8 + kk) * 32 + blk * 8 + jj],
                               acc);
                }
                hn[blk * 8 + jj] = fmaxf(acc, 0.f);
            }
        }
#pragma unroll
        for (int j = 0; j < 32; ++j) h[j] = hn[j];
    }

    // ---- block-diagonal output layer: 8 blocks of 4x3
    float o[24];
#pragma unroll
    for (int i = 0; i < 8; ++i) {
#pragma unroll
        for (int c = 0; c < 3; ++c) {
            float acc = 0.f;
#pragma unroll
            for (int s = 0; s < 4; ++s) {
                acc = fmaf(h[4 * i + s],
                           Wout[(4 * i + s) * 24 + 3 * i + c],
                           acc);
            }
            o[3 * i + c] = acc;
        }
    }

    if (row < B) {
        float4* __restrict__ o4 =
            reinterpret_cast<float4*>(out) + (size_t)row * 6;
#pragma unroll
        for (int q = 0; q < 6; ++q) {
            o4[q] = make_float4(o[4 * q + 0], o[4 * q + 1],
                                o[4 * q + 2], o[4 * q + 3]);
        }
    }
}

extern "C" void kernel_launch(void* const* d_in, const int* in_sizes, int n_in,
                              void* d_out, int out_size, void* d_ws, size_t ws_size,
                              hipStream_t stream)
{
    const float* x    = (const float*)d_in[0];  // [B,64]
    const float* Win  = (const float*)d_in[1];  // [64,32]
    const float* Wh   = (const float*)d_in[2];  // [4,32,32]
    const float* Wout = (const float*)d_in[3];  // [32,24]
    float* out        = (float*)d_out;          // [B,24]

    int B = in_sizes[0] / 64;
    int blocks = (B + 255) / 256;
    bd_mlp_kernel<<<blocks, 256, 0, stream>>>(x, Win, Wh, Wout, out, B);
}